// Round 5
// baseline (181.657 us; speedup 1.0000x reference)
//
#include <hip/hip_runtime.h>
#include <stdint.h>
#include <stddef.h>

#define N 2048
#define KMX 192
#define NTHREADS 1024

// ---------------- Threefry-2x32, JAX-compatible (20 rounds) ----------------
__device__ __forceinline__ void tfround(unsigned &x0, unsigned &x1, const int d) {
  x0 += x1;
  x1 = (x1 << d) | (x1 >> (32 - d));
  x1 ^= x0;
}

__device__ __forceinline__ uint2 tf2x32(unsigned k0, unsigned k1, unsigned c0, unsigned c1) {
  unsigned ks2 = k0 ^ k1 ^ 0x1BD11BDAu;
  unsigned x0 = c0 + k0, x1 = c1 + k1;
  tfround(x0,x1,13); tfround(x0,x1,15); tfround(x0,x1,26); tfround(x0,x1,6);
  x0 += k1;  x1 += ks2 + 1u;
  tfround(x0,x1,17); tfround(x0,x1,29); tfround(x0,x1,16); tfround(x0,x1,24);
  x0 += ks2; x1 += k0 + 2u;
  tfround(x0,x1,13); tfround(x0,x1,15); tfround(x0,x1,26); tfround(x0,x1,6);
  x0 += k0;  x1 += k1 + 3u;
  tfround(x0,x1,17); tfround(x0,x1,29); tfround(x0,x1,16); tfround(x0,x1,24);
  x0 += k1;  x1 += ks2 + 4u;
  tfround(x0,x1,13); tfround(x0,x1,15); tfround(x0,x1,26); tfround(x0,x1,6);
  x0 += ks2; x1 += k0 + 5u;
  uint2 r; r.x = x0; r.y = x1;
  return r;
}

// JAX uniform [0,1): (bits>>9 | 0x3f800000) bitcast - 1.0f  (exact)
__device__ __forceinline__ float u01(unsigned bits) {
  return __uint_as_float((bits >> 9) | 0x3f800000u) - 1.0f;
}

// ---------------- Kernel 1: Bernoulli selection + key derivation ----------------
// key = (0, seed); partitionable split: k_idx = tf(key,(0,0)), k_loop = tf(key,(0,1))
// index_i = u01(tf(k_idx,(0,i)).x ^ .y) < e_i/(e_i+1)   (bit-exact vs JAX)
// hdr[0]=kk=min(k,KMX), hdr[1]=k, hdr[2..3]=k_loop; sel[0..kk) = selected idx ascending
__global__ void k_select(const float* __restrict__ e, const int* __restrict__ seedp,
                         int* __restrict__ hdr, int* __restrict__ sel) {
  __shared__ unsigned kx0, kx1;
  __shared__ int cnt_s[256];
  __shared__ int pre_s[256];
  const int tid = threadIdx.x;
  if (tid == 0) {
    unsigned seed = (unsigned)seedp[0];
    uint2 kidx  = tf2x32(0u, seed, 0u, 0u);
    uint2 kloop = tf2x32(0u, seed, 0u, 1u);
    kx0 = kidx.x; kx1 = kidx.y;
    hdr[2] = (int)kloop.x;
    hdr[3] = (int)kloop.y;
  }
  __syncthreads();
  const unsigned a0 = kx0, a1 = kx1;
  int flags = 0;
  #pragma unroll
  for (int r = 0; r < 8; ++r) {
    const int i = tid * 8 + r;
    uint2 o = tf2x32(a0, a1, 0u, (unsigned)i);
    float u = u01(o.x ^ o.y);
    float ev = e[i];
    float thr = ev / (ev + 1.0f);   // IEEE f32 div, matches XLA CPU bit-exactly
    if (u < thr) flags |= (1 << r);
  }
  cnt_s[tid] = __popc(flags);
  __syncthreads();
  if (tid == 0) {
    int acc = 0;
    for (int t2 = 0; t2 < 256; ++t2) { pre_s[t2] = acc; acc += cnt_s[t2]; }
    hdr[1] = acc;
    hdr[0] = acc < KMX ? acc : KMX;
  }
  __syncthreads();
  int off = pre_s[tid];
  #pragma unroll
  for (int r = 0; r < 8; ++r) {
    if (flags & (1 << r)) {
      if (off < KMX) sel[off] = tid * 8 + r;
      ++off;
    }
  }
}

// ---------------- Kernel 2: gather G (column-major, G[j][i] = v[i, sel[j]]) ----------------
__global__ void k_gather(const float* __restrict__ v, const int* __restrict__ hdr,
                         const int* __restrict__ sel, float* __restrict__ G) {
  const int j = blockIdx.y;
  if (j >= hdr[0]) return;
  const int col = sel[j];
  const int i = blockIdx.x * 256 + threadIdx.x;
  G[j * N + i] = v[(size_t)i * N + col];
}

// ---------------- Kernel 3: sequential DPP loop (single block) ----------------
// Maintains p_i = ||proj_{S_t} e_i||^2 incrementally; subspace tracked by
// orthonormal removed-directions U (rows of D) in coefficient space (dim kk).
__global__ void __launch_bounds__(NTHREADS)
k_dpp_main(const int* __restrict__ hdr, const float* __restrict__ G,
           float* __restrict__ D, float* __restrict__ out) {
  __shared__ float p_s[N];
  __shared__ float g_s[KMX];
  __shared__ float q_s[KMX];
  __shared__ float wsum_s[16], wpre_s[16];
  __shared__ float u_sh, S_sh, rho_sh;
  __shared__ int item_sh;

  const int tid  = threadIdx.x;
  const int lane = tid & 63;
  const int wave = tid >> 6;
  const int kk    = hdr[0];
  const int kfull = hdr[1];
  const unsigned kl0 = (unsigned)hdr[2];
  const unsigned kl1 = (unsigned)hdr[3];

  // init output (d_out is poisoned; rewrite deterministically every call)
  const float fill = (kfull == N) ? 1.0f : 0.0f;   // reference: k==n -> all ones
  out[tid] = fill;
  out[tid + NTHREADS] = fill;
  if (kfull == N || kk == 0) return;

  // initial p_i = ||G_i||^2 (columns j, coalesced)
  float p0 = 0.f, p1 = 0.f;
  for (int j = 0; j < kk; ++j) {
    float a = G[j * N + tid];
    float b = G[j * N + tid + NTHREADS];
    p0 = fmaf(a, a, p0);
    p1 = fmaf(b, b, p1);
  }
  p_s[tid] = p0;
  p_s[tid + NTHREADS] = p1;
  __syncthreads();

  for (int t = 0; t < kk; ++t) {
    // ---- c = cumsum(p/S); item = first index with u < c ----
    float a = p_s[2 * tid];
    float b = p_s[2 * tid + 1];
    float ts = a + b;
    float ws = ts;
    #pragma unroll
    for (int d = 1; d < 64; d <<= 1) {
      float o = __shfl_up(ws, d, 64);
      if (lane >= d) ws += o;
    }
    if (lane == 63) wsum_s[wave] = ws;
    __syncthreads();
    if (tid == 0) {
      float acc = 0.f;
      #pragma unroll
      for (int w = 0; w < 16; ++w) { wpre_s[w] = acc; acc += wsum_s[w]; }
      S_sh = acc;
      item_sh = N;
      // u = uniform(fold_in(k_loop, t)):
      // fold_in -> tf(k_loop,(0,t)); bits = x^y of tf(folded,(0,0))
      uint2 fk = tf2x32(kl0, kl1, 0u, (unsigned)t);
      uint2 ob = tf2x32(fk.x, fk.y, 0u, 0u);
      u_sh = u01(ob.x ^ ob.y);
    }
    __syncthreads();
    const float S = S_sh;
    const float u = u_sh;
    float excl = __shfl_up(ws, 1, 64);
    if (lane == 0) excl = 0.f;
    const float base = wpre_s[wave] + excl;
    const float c0 = (base + a) / S;
    const float c1 = (base + ts) / S;
    int cand = N;
    if (u < c0) cand = 2 * tid;
    else if (u < c1) cand = 2 * tid + 1;
    if (cand < N) atomicMin(&item_sh, cand);
    __syncthreads();
    int item = item_sh;
    if (item >= N) item = 0;          // argmax of all-False == 0 (matches jnp)
    if (tid == 0) out[item] = 1.0f;
    if (t == kk - 1) break;           // reference: m==1 -> no update

    // ---- g = G[item, :] ----
    if (tid < kk) g_s[tid] = G[tid * N + item];
    __syncthreads();

    // ---- delta = (I - U U^T) g, CGS with reorthogonalization (2 passes) ----
    for (int pass = 0; pass < 2; ++pass) {
      for (int s = wave; s < t; s += 16) {
        float acc = 0.f;
        for (int j = lane; j < kk; j += 64) acc += D[s * KMX + j] * g_s[j];
        #pragma unroll
        for (int d = 32; d > 0; d >>= 1) acc += __shfl_down(acc, d, 64);
        if (lane == 0) q_s[s] = acc;
      }
      __syncthreads();
      if (tid < kk) {
        float gg = g_s[tid];
        for (int s = 0; s < t; ++s) gg -= q_s[s] * D[s * KMX + tid];
        g_s[tid] = gg;
      }
      __syncthreads();
    }

    // ---- normalize, append to U ----
    if (tid == 0) {
      float r2 = 0.f;
      for (int j = 0; j < kk; ++j) r2 += g_s[j] * g_s[j];
      rho_sh = sqrtf(r2);
    }
    __syncthreads();
    if (tid < kk) {
      float dj = g_s[tid] / rho_sh;
      g_s[tid] = dj;
      D[t * KMX + tid] = dj;
    }
    __syncthreads();

    // ---- p_i -= (G_i . delta)^2 ; clamp >= 0 (reference p is a sum of squares) ----
    float s0 = 0.f, s1 = 0.f;
    for (int j = 0; j < kk; ++j) {
      float dj = g_s[j];
      s0 = fmaf(G[j * N + tid], dj, s0);
      s1 = fmaf(G[j * N + tid + NTHREADS], dj, s1);
    }
    p_s[tid]            = fmaxf(p_s[tid]            - s0 * s0, 0.f);
    p_s[tid + NTHREADS] = fmaxf(p_s[tid + NTHREADS] - s1 * s1, 0.f);
    __syncthreads();
  }
}

extern "C" void kernel_launch(void* const* d_in, const int* in_sizes, int n_in,
                              void* d_out, int out_size, void* d_ws, size_t ws_size,
                              hipStream_t stream) {
  (void)in_sizes; (void)n_in; (void)out_size; (void)ws_size;
  const float* e    = (const float*)d_in[0];
  const float* v    = (const float*)d_in[1];
  const int*   seed = (const int*)d_in[2];
  float* out = (float*)d_out;

  // ws layout: [0..32) hdr (kk, k, kloop0, kloop1); [32..800) sel[192];
  // [1024..148480) D (192x192 f32); [256KiB..256KiB+1.5MiB) G (192x2048 f32, col-major)
  int* hdr = (int*)d_ws;
  int* sel = hdr + 8;
  float* D = (float*)((char*)d_ws + 1024);
  float* G = (float*)((char*)d_ws + (size_t)256 * 1024);

  k_select<<<1, 256, 0, stream>>>(e, seed, hdr, sel);
  k_gather<<<dim3(8, KMX), 256, 0, stream>>>(v, hdr, sel, G);
  k_dpp_main<<<1, NTHREADS, 0, stream>>>(hdr, G, D, out);
}

// Round 6
// 156.651 us; speedup vs baseline: 1.1596x; 1.1596x over previous
//
#include <hip/hip_runtime.h>
#include <stdint.h>
#include <stddef.h>

#define N 2048
#define KMX 192
#define NTH 1024

// ---------------- Threefry-2x32, JAX-compatible (20 rounds) ----------------
__device__ __forceinline__ void tfround(unsigned &x0, unsigned &x1, const int d) {
  x0 += x1;
  x1 = (x1 << d) | (x1 >> (32 - d));
  x1 ^= x0;
}

__device__ __forceinline__ uint2 tf2x32(unsigned k0, unsigned k1, unsigned c0, unsigned c1) {
  unsigned ks2 = k0 ^ k1 ^ 0x1BD11BDAu;
  unsigned x0 = c0 + k0, x1 = c1 + k1;
  tfround(x0,x1,13); tfround(x0,x1,15); tfround(x0,x1,26); tfround(x0,x1,6);
  x0 += k1;  x1 += ks2 + 1u;
  tfround(x0,x1,17); tfround(x0,x1,29); tfround(x0,x1,16); tfround(x0,x1,24);
  x0 += ks2; x1 += k0 + 2u;
  tfround(x0,x1,13); tfround(x0,x1,15); tfround(x0,x1,26); tfround(x0,x1,6);
  x0 += k0;  x1 += k1 + 3u;
  tfround(x0,x1,17); tfround(x0,x1,29); tfround(x0,x1,16); tfround(x0,x1,24);
  x0 += k1;  x1 += ks2 + 4u;
  tfround(x0,x1,13); tfround(x0,x1,15); tfround(x0,x1,26); tfround(x0,x1,6);
  x0 += ks2; x1 += k0 + 5u;
  uint2 r; r.x = x0; r.y = x1;
  return r;
}

// JAX uniform [0,1): (bits>>9 | 0x3f800000) bitcast - 1.0f  (exact)
__device__ __forceinline__ float u01(unsigned bits) {
  return __uint_as_float((bits >> 9) | 0x3f800000u) - 1.0f;
}

// ---------------- Kernel 1: Bernoulli selection + key derivation ----------------
__global__ void k_select(const float* __restrict__ e, const int* __restrict__ seedp,
                         int* __restrict__ hdr, int* __restrict__ sel) {
  __shared__ unsigned kx0, kx1;
  __shared__ int cnt_s[256];
  __shared__ int pre_s[256];
  const int tid = threadIdx.x;
  if (tid == 0) {
    unsigned seed = (unsigned)seedp[0];
    uint2 kidx  = tf2x32(0u, seed, 0u, 0u);
    uint2 kloop = tf2x32(0u, seed, 0u, 1u);
    kx0 = kidx.x; kx1 = kidx.y;
    hdr[2] = (int)kloop.x;
    hdr[3] = (int)kloop.y;
  }
  __syncthreads();
  const unsigned a0 = kx0, a1 = kx1;
  int flags = 0;
  #pragma unroll
  for (int r = 0; r < 8; ++r) {
    const int i = tid * 8 + r;
    uint2 o = tf2x32(a0, a1, 0u, (unsigned)i);
    float u = u01(o.x ^ o.y);
    float ev = e[i];
    float thr = ev / (ev + 1.0f);   // IEEE f32 div, matches XLA bit-exactly
    if (u < thr) flags |= (1 << r);
  }
  cnt_s[tid] = __popc(flags);
  __syncthreads();
  if (tid == 0) {
    int acc = 0;
    for (int t2 = 0; t2 < 256; ++t2) { pre_s[t2] = acc; acc += cnt_s[t2]; }
    hdr[1] = acc;
    hdr[0] = acc < KMX ? acc : KMX;
  }
  __syncthreads();
  int off = pre_s[tid];
  #pragma unroll
  for (int r = 0; r < 8; ++r) {
    if (flags & (1 << r)) {
      if (off < KMX) sel[off] = tid * 8 + r;
      ++off;
    }
  }
}

// ---------------- Kernel 2: gather G (col-major G[j][i] = v[i, sel[j]]), zero-pad j>=kk ----
__global__ void k_gather(const float* __restrict__ v, const int* __restrict__ hdr,
                         const int* __restrict__ sel, float* __restrict__ G) {
  const int j = blockIdx.y;
  const int i = blockIdx.x * 256 + threadIdx.x;
  float val = 0.f;
  if (j < hdr[0]) val = v[(size_t)i * N + sel[j]];
  G[j * N + i] = val;
}

// ---------------- Kernel 3: sequential DPP loop (single block, 16 waves) ----------------
// p_i = ||proj e_i||^2 tracked incrementally; removed-directions (rows of D, dim KMX,
// zero-padded) kept orthonormal via merged-CGS2 (butterfly-allreduce dots fused with update).
__global__ void __launch_bounds__(NTH)
k_dpp_main(const int* __restrict__ hdr, const float* __restrict__ G,
           float* __restrict__ D, float* __restrict__ out) {
  __shared__ float p_s[N];          // p_s[i], row i owned by thread i/2
  __shared__ float g_s[KMX];
  __shared__ float part[16 * KMX];  // per-wave update partials
  __shared__ float u_s[KMX];        // precomputed uniforms for all iterations
  __shared__ float wsum_s[16];
  __shared__ int item_sh;

  const int tid  = threadIdx.x;
  const int lane = tid & 63;
  const int wave = tid >> 6;
  const int kk    = hdr[0];
  const int kfull = hdr[1];
  const unsigned kl0 = (unsigned)hdr[2];
  const unsigned kl1 = (unsigned)hdr[3];

  const float fill = (kfull == N) ? 1.0f : 0.0f;   // reference: k==n -> all ones
  out[tid] = fill;
  out[tid + NTH] = fill;
  if (kfull == N || kk == 0) return;

  const int kkr = (kk + 15) & ~15;                  // padded col count (G cols >= kk are 0)
  const float2* __restrict__ G2 = (const float2*)G; // G2[j*(N/2) + i2] = rows 2*i2, 2*i2+1

  // ---- init: p_i = ||G_i||^2 (rows 2tid, 2tid+1); precompute all u_t; reset item ----
  {
    float s0a = 0.f, s0b = 0.f, s1a = 0.f, s1b = 0.f;
    for (int j = 0; j < kkr; j += 4) {
      float2 x0 = G2[(j + 0) * (N / 2) + tid];
      float2 x1 = G2[(j + 1) * (N / 2) + tid];
      float2 x2 = G2[(j + 2) * (N / 2) + tid];
      float2 x3 = G2[(j + 3) * (N / 2) + tid];
      s0a = fmaf(x0.x, x0.x, s0a); s1a = fmaf(x0.y, x0.y, s1a);
      s0b = fmaf(x1.x, x1.x, s0b); s1b = fmaf(x1.y, x1.y, s1b);
      s0a = fmaf(x2.x, x2.x, s0a); s1a = fmaf(x2.y, x2.y, s1a);
      s0b = fmaf(x3.x, x3.x, s0b); s1b = fmaf(x3.y, x3.y, s1b);
    }
    p_s[2 * tid]     = s0a + s0b;
    p_s[2 * tid + 1] = s1a + s1b;
    if (tid < KMX) {
      // u_t = uniform(fold_in(k_loop, t)) — all iterations, computed once in parallel
      uint2 fk = tf2x32(kl0, kl1, 0u, (unsigned)tid);
      uint2 ob = tf2x32(fk.x, fk.y, 0u, 0u);
      u_s[tid] = u01(ob.x ^ ob.y);
    }
    if (tid == 0) item_sh = N;
  }
  __syncthreads();

  for (int t = 0; t < kk; ++t) {
    // ---- selection: find first i with u < cumsum(p)_i / S (min-index semantics) ----
    float a  = p_s[2 * tid];
    float b  = p_s[2 * tid + 1];
    float ts = a + b;
    float ws = ts;
    #pragma unroll
    for (int d = 1; d < 64; d <<= 1) {
      float o = __shfl_up(ws, d, 64);
      if (lane >= d) ws += o;
    }
    if (lane == 63) wsum_s[wave] = ws;
    __syncthreads();                                   // (A)
    float S = 0.f, base_wave = 0.f;
    #pragma unroll
    for (int w = 0; w < 16; ++w) {
      float wv = wsum_s[w];
      if (w < wave) base_wave += wv;
      S += wv;
    }
    const float u = u_s[t];
    float excl = __shfl_up(ws, 1, 64);
    if (lane == 0) excl = 0.f;
    const float base = base_wave + excl;
    const float c0 = (base + a) / S;
    const float c1 = (base + ts) / S;
    const bool m0 = (u < c0);
    const bool m1 = (u < c1);
    unsigned long long bal = __ballot(m0 || m1);
    if (bal) {
      int first = (int)__builtin_ctzll(bal);           // first matching lane in wave
      if (lane == first) atomicMin(&item_sh, m0 ? 2 * tid : 2 * tid + 1);
    }
    __syncthreads();                                   // (B)
    int item = item_sh;
    if (item >= N) item = 0;                           // argmax(all False) == 0
    if (tid == 0) out[item] = 1.0f;
    if (t == kk - 1) break;                            // reference: m==1 -> no update

    // ---- gather g = G[:, item] (zero-padded rows j>=kk give g_s[j]=0) ----
    if (tid < KMX) g_s[tid] = G[tid * N + item];
    __syncthreads();                                   // (C)

    // ---- CGS pass 1: g -= U U^T g (dot fused with update; D row loaded once) ----
    {
      float g0 = g_s[lane], g1 = g_s[lane + 64], g2 = g_s[lane + 128];
      float a0 = 0.f, a1 = 0.f, a2 = 0.f;
      for (int s = wave; s < t; s += 16) {
        const float* Dr = D + s * KMX;
        float d0 = Dr[lane], d1 = Dr[lane + 64], d2 = Dr[lane + 128];
        float acc = fmaf(d0, g0, fmaf(d1, g1, d2 * g2));
        #pragma unroll
        for (int m = 1; m < 64; m <<= 1) acc += __shfl_xor(acc, m, 64);
        a0 = fmaf(acc, d0, a0); a1 = fmaf(acc, d1, a1); a2 = fmaf(acc, d2, a2);
      }
      part[wave * KMX + lane]       = a0;
      part[wave * KMX + lane + 64]  = a1;
      part[wave * KMX + lane + 128] = a2;
    }
    __syncthreads();                                   // (D)
    if (tid < KMX) {
      float gg = g_s[tid];
      #pragma unroll
      for (int w = 0; w < 16; ++w) gg -= part[w * KMX + tid];
      g_s[tid] = gg;
    }
    __syncthreads();                                   // (E)

    // ---- CGS pass 2 (reorthogonalization) + rho ----
    float gg2 = 0.f;
    {
      float g0 = g_s[lane], g1 = g_s[lane + 64], g2 = g_s[lane + 128];
      float a0 = 0.f, a1 = 0.f, a2 = 0.f;
      for (int s = wave; s < t; s += 16) {
        const float* Dr = D + s * KMX;
        float d0 = Dr[lane], d1 = Dr[lane + 64], d2 = Dr[lane + 128];
        float acc = fmaf(d0, g0, fmaf(d1, g1, d2 * g2));
        #pragma unroll
        for (int m = 1; m < 64; m <<= 1) acc += __shfl_xor(acc, m, 64);
        a0 = fmaf(acc, d0, a0); a1 = fmaf(acc, d1, a1); a2 = fmaf(acc, d2, a2);
      }
      part[wave * KMX + lane]       = a0;
      part[wave * KMX + lane + 64]  = a1;
      part[wave * KMX + lane + 128] = a2;
    }
    __syncthreads();                                   // (F)
    if (tid < KMX) {
      float gg = g_s[tid];
      #pragma unroll
      for (int w = 0; w < 16; ++w) gg -= part[w * KMX + tid];
      gg2 = gg;
    }
    if (wave < 3) {                                    // rho^2 = sum over 192 slots
      float r = gg2 * gg2;
      #pragma unroll
      for (int m = 1; m < 64; m <<= 1) r += __shfl_xor(r, m, 64);
      if (lane == 0) wsum_s[wave] = r;
    }
    __syncthreads();                                   // (G)
    const float rho = sqrtf(wsum_s[0] + wsum_s[1] + wsum_s[2]);
    if (tid < KMX) {
      float dj = gg2 / rho;
      g_s[tid] = dj;
      D[t * KMX + tid] = dj;                           // rows stay zero-padded (gg2=0 there)
    }
    if (tid == 0) item_sh = N;                         // reset for next iteration
    __syncthreads();                                   // (H)

    // ---- p_i -= (G_i . delta)^2, clamp >= 0 (rows 2tid, 2tid+1; no trailing barrier) ----
    {
      float s0a = 0.f, s0b = 0.f, s1a = 0.f, s1b = 0.f;
      for (int j = 0; j < kkr; j += 4) {
        float d0 = g_s[j], d1 = g_s[j + 1], d2 = g_s[j + 2], d3 = g_s[j + 3];
        float2 x0 = G2[(j + 0) * (N / 2) + tid];
        float2 x1 = G2[(j + 1) * (N / 2) + tid];
        float2 x2 = G2[(j + 2) * (N / 2) + tid];
        float2 x3 = G2[(j + 3) * (N / 2) + tid];
        s0a = fmaf(x0.x, d0, s0a); s1a = fmaf(x0.y, d0, s1a);
        s0b = fmaf(x1.x, d1, s0b); s1b = fmaf(x1.y, d1, s1b);
        s0a = fmaf(x2.x, d2, s0a); s1a = fmaf(x2.y, d2, s1a);
        s0b = fmaf(x3.x, d3, s0b); s1b = fmaf(x3.y, d3, s1b);
      }
      float s0 = s0a + s0b, s1 = s1a + s1b;
      p_s[2 * tid]     = fmaxf(p_s[2 * tid]     - s0 * s0, 0.f);
      p_s[2 * tid + 1] = fmaxf(p_s[2 * tid + 1] - s1 * s1, 0.f);
    }
    // p_s rows are thread-private; wsum_s/item_sh next writes are separated by barriers A/B.
  }
}

extern "C" void kernel_launch(void* const* d_in, const int* in_sizes, int n_in,
                              void* d_out, int out_size, void* d_ws, size_t ws_size,
                              hipStream_t stream) {
  (void)in_sizes; (void)n_in; (void)out_size; (void)ws_size;
  const float* e    = (const float*)d_in[0];
  const float* v    = (const float*)d_in[1];
  const int*   seed = (const int*)d_in[2];
  float* out = (float*)d_out;

  // ws layout: [0..32) hdr (kk, k, kloop0, kloop1); [32..800) sel[192];
  // [1024..148480) D (192x192 f32); [256KiB..256KiB+1.5MiB) G (192x2048 f32, col-major)
  int* hdr = (int*)d_ws;
  int* sel = hdr + 8;
  float* D = (float*)((char*)d_ws + 1024);
  float* G = (float*)((char*)d_ws + (size_t)256 * 1024);

  k_select<<<1, 256, 0, stream>>>(e, seed, hdr, sel);
  k_gather<<<dim3(8, KMX), 256, 0, stream>>>(v, hdr, sel, G);
  k_dpp_main<<<1, NTH, 0, stream>>>(hdr, G, D, out);
}

// Round 7
// 109.194 us; speedup vs baseline: 1.6636x; 1.4346x over previous
//
#include <hip/hip_runtime.h>
#include <hip/hip_fp16.h>
#include <stdint.h>
#include <stddef.h>

#define N 2048
#define KMX 192
#define NTH 1024

// ---------------- Threefry-2x32, JAX-compatible (20 rounds) ----------------
__device__ __forceinline__ void tfround(unsigned &x0, unsigned &x1, const int d) {
  x0 += x1;
  x1 = (x1 << d) | (x1 >> (32 - d));
  x1 ^= x0;
}

__device__ __forceinline__ uint2 tf2x32(unsigned k0, unsigned k1, unsigned c0, unsigned c1) {
  unsigned ks2 = k0 ^ k1 ^ 0x1BD11BDAu;
  unsigned x0 = c0 + k0, x1 = c1 + k1;
  tfround(x0,x1,13); tfround(x0,x1,15); tfround(x0,x1,26); tfround(x0,x1,6);
  x0 += k1;  x1 += ks2 + 1u;
  tfround(x0,x1,17); tfround(x0,x1,29); tfround(x0,x1,16); tfround(x0,x1,24);
  x0 += ks2; x1 += k0 + 2u;
  tfround(x0,x1,13); tfround(x0,x1,15); tfround(x0,x1,26); tfround(x0,x1,6);
  x0 += k0;  x1 += k1 + 3u;
  tfround(x0,x1,17); tfround(x0,x1,29); tfround(x0,x1,16); tfround(x0,x1,24);
  x0 += k1;  x1 += ks2 + 4u;
  tfround(x0,x1,13); tfround(x0,x1,15); tfround(x0,x1,26); tfround(x0,x1,6);
  x0 += ks2; x1 += k0 + 5u;
  uint2 r; r.x = x0; r.y = x1;
  return r;
}

// JAX uniform [0,1): (bits>>9 | 0x3f800000) bitcast - 1.0f  (exact)
__device__ __forceinline__ float u01(unsigned bits) {
  return __uint_as_float((bits >> 9) | 0x3f800000u) - 1.0f;
}

// ---------------- Kernel 1: Bernoulli selection + key derivation ----------------
__global__ void k_select(const float* __restrict__ e, const int* __restrict__ seedp,
                         int* __restrict__ hdr, int* __restrict__ sel) {
  __shared__ unsigned kx0, kx1;
  __shared__ int cnt_s[256];
  __shared__ int pre_s[256];
  const int tid = threadIdx.x;
  if (tid == 0) {
    unsigned seed = (unsigned)seedp[0];
    uint2 kidx  = tf2x32(0u, seed, 0u, 0u);
    uint2 kloop = tf2x32(0u, seed, 0u, 1u);
    kx0 = kidx.x; kx1 = kidx.y;
    hdr[2] = (int)kloop.x;
    hdr[3] = (int)kloop.y;
  }
  __syncthreads();
  const unsigned a0 = kx0, a1 = kx1;
  int flags = 0;
  #pragma unroll
  for (int r = 0; r < 8; ++r) {
    const int i = tid * 8 + r;
    uint2 o = tf2x32(a0, a1, 0u, (unsigned)i);
    float u = u01(o.x ^ o.y);
    float ev = e[i];
    float thr = ev / (ev + 1.0f);   // IEEE f32 div, matches XLA bit-exactly
    if (u < thr) flags |= (1 << r);
  }
  cnt_s[tid] = __popc(flags);
  __syncthreads();
  if (tid == 0) {
    int acc = 0;
    for (int t2 = 0; t2 < 256; ++t2) { pre_s[t2] = acc; acc += cnt_s[t2]; }
    hdr[1] = acc;
    hdr[0] = acc < KMX ? acc : KMX;
  }
  __syncthreads();
  int off = pre_s[tid];
  #pragma unroll
  for (int r = 0; r < 8; ++r) {
    if (flags & (1 << r)) {
      if (off < KMX) sel[off] = tid * 8 + r;
      ++off;
    }
  }
}

// ---------------- Kernel 2: gather G f32 + Gh fp16 mirror (col-major, zero-pad j>=kk) ----
__global__ void k_gather(const float* __restrict__ v, const int* __restrict__ hdr,
                         const int* __restrict__ sel, float* __restrict__ G,
                         __half* __restrict__ Gh) {
  const int j = blockIdx.y;
  const int i = blockIdx.x * 256 + threadIdx.x;
  float val = 0.f;
  if (j < hdr[0]) val = v[(size_t)i * N + sel[j]];
  G[j * N + i] = val;
  Gh[j * N + i] = __float2half(val);
}

// ---------------- Kernel 3: sequential DPP loop (single block, 16 waves) ----------------
// p_i = ||proj e_i||^2 tracked incrementally; removed-directions (rows of D, dim KMX,
// zero-padded) kept orthonormal via merged-CGS2. p-scan reads fp16 Gh (f32 accumulate);
// CGS / g-gather / D stay f32.
__global__ void __launch_bounds__(NTH)
k_dpp_main(const int* __restrict__ hdr, const float* __restrict__ G,
           const __half* __restrict__ Gh, float* __restrict__ D,
           float* __restrict__ out) {
  __shared__ float p_s[N];          // p_s[i], row i owned by thread i/2
  __shared__ float g_s[KMX];
  __shared__ float part[16 * KMX];  // per-wave update partials
  __shared__ float u_s[KMX];        // precomputed uniforms for all iterations
  __shared__ float wsum_s[16];
  __shared__ int item_sh;

  const int tid  = threadIdx.x;
  const int lane = tid & 63;
  const int wave = tid >> 6;
  const int kk    = hdr[0];
  const int kfull = hdr[1];
  const unsigned kl0 = (unsigned)hdr[2];
  const unsigned kl1 = (unsigned)hdr[3];

  const float fill = (kfull == N) ? 1.0f : 0.0f;   // reference: k==n -> all ones
  out[tid] = fill;
  out[tid + NTH] = fill;
  if (kfull == N || kk == 0) return;

  const int kkr = (kk + 15) & ~15;                  // padded col count (cols >= kk are 0)

  // ---- init: p_i = ||Gh_i||^2 (rows 2tid, 2tid+1); precompute all u_t; reset item ----
  {
    float s0a = 0.f, s0b = 0.f, s1a = 0.f, s1b = 0.f;
    const __half* base = Gh + 2 * tid;
    for (int j = 0; j < kkr; j += 4) {
      float2 f0 = __half22float2(*(const __half2*)(base + (j + 0) * N));
      float2 f1 = __half22float2(*(const __half2*)(base + (j + 1) * N));
      float2 f2 = __half22float2(*(const __half2*)(base + (j + 2) * N));
      float2 f3 = __half22float2(*(const __half2*)(base + (j + 3) * N));
      s0a = fmaf(f0.x, f0.x, s0a); s1a = fmaf(f0.y, f0.y, s1a);
      s0b = fmaf(f1.x, f1.x, s0b); s1b = fmaf(f1.y, f1.y, s1b);
      s0a = fmaf(f2.x, f2.x, s0a); s1a = fmaf(f2.y, f2.y, s1a);
      s0b = fmaf(f3.x, f3.x, s0b); s1b = fmaf(f3.y, f3.y, s1b);
    }
    p_s[2 * tid]     = s0a + s0b;
    p_s[2 * tid + 1] = s1a + s1b;
    if (tid < KMX) {
      // u_t = uniform(fold_in(k_loop, t)) — all iterations, computed once in parallel
      uint2 fk = tf2x32(kl0, kl1, 0u, (unsigned)tid);
      uint2 ob = tf2x32(fk.x, fk.y, 0u, 0u);
      u_s[tid] = u01(ob.x ^ ob.y);
    }
    if (tid == 0) item_sh = N;
  }
  __syncthreads();

  for (int t = 0; t < kk; ++t) {
    // ---- selection: find first i with u < cumsum(p)_i / S (min-index semantics) ----
    float a  = p_s[2 * tid];
    float b  = p_s[2 * tid + 1];
    float ts = a + b;
    float ws = ts;
    #pragma unroll
    for (int d = 1; d < 64; d <<= 1) {
      float o = __shfl_up(ws, d, 64);
      if (lane >= d) ws += o;
    }
    if (lane == 63) wsum_s[wave] = ws;
    __syncthreads();                                   // (A)
    float S = 0.f, base_wave = 0.f;
    #pragma unroll
    for (int w = 0; w < 16; ++w) {
      float wv = wsum_s[w];
      if (w < wave) base_wave += wv;
      S += wv;
    }
    const float u = u_s[t];
    float excl = __shfl_up(ws, 1, 64);
    if (lane == 0) excl = 0.f;
    const float base = base_wave + excl;
    const float c0 = (base + a) / S;
    const float c1 = (base + ts) / S;
    const bool m0 = (u < c0);
    const bool m1 = (u < c1);
    unsigned long long bal = __ballot(m0 || m1);
    if (bal) {
      int first = (int)__builtin_ctzll(bal);           // first matching lane in wave
      if (lane == first) atomicMin(&item_sh, m0 ? 2 * tid : 2 * tid + 1);
    }
    __syncthreads();                                   // (B)
    int item = item_sh;
    if (item >= N) item = 0;                           // argmax(all False) == 0
    if (tid == 0) out[item] = 1.0f;
    if (t == kk - 1) break;                            // reference: m==1 -> no update

    // ---- gather g = G[:, item] (f32; zero-padded rows j>=kk give g_s[j]=0) ----
    if (tid < KMX) g_s[tid] = G[tid * N + item];
    __syncthreads();                                   // (C)

    // ---- CGS pass 1: g -= U U^T g (dot fused with update; D row loaded once) ----
    {
      float g0 = g_s[lane], g1 = g_s[lane + 64], g2 = g_s[lane + 128];
      float a0 = 0.f, a1 = 0.f, a2 = 0.f;
      for (int s = wave; s < t; s += 16) {
        const float* Dr = D + s * KMX;
        float d0 = Dr[lane], d1 = Dr[lane + 64], d2 = Dr[lane + 128];
        float acc = fmaf(d0, g0, fmaf(d1, g1, d2 * g2));
        #pragma unroll
        for (int m = 1; m < 64; m <<= 1) acc += __shfl_xor(acc, m, 64);
        a0 = fmaf(acc, d0, a0); a1 = fmaf(acc, d1, a1); a2 = fmaf(acc, d2, a2);
      }
      part[wave * KMX + lane]       = a0;
      part[wave * KMX + lane + 64]  = a1;
      part[wave * KMX + lane + 128] = a2;
    }
    __syncthreads();                                   // (D)
    if (tid < KMX) {
      float gg = g_s[tid];
      #pragma unroll
      for (int w = 0; w < 16; ++w) gg -= part[w * KMX + tid];
      g_s[tid] = gg;
    }
    __syncthreads();                                   // (E)

    // ---- CGS pass 2 (reorthogonalization) + rho ----
    float gg2 = 0.f;
    {
      float g0 = g_s[lane], g1 = g_s[lane + 64], g2 = g_s[lane + 128];
      float a0 = 0.f, a1 = 0.f, a2 = 0.f;
      for (int s = wave; s < t; s += 16) {
        const float* Dr = D + s * KMX;
        float d0 = Dr[lane], d1 = Dr[lane + 64], d2 = Dr[lane + 128];
        float acc = fmaf(d0, g0, fmaf(d1, g1, d2 * g2));
        #pragma unroll
        for (int m = 1; m < 64; m <<= 1) acc += __shfl_xor(acc, m, 64);
        a0 = fmaf(acc, d0, a0); a1 = fmaf(acc, d1, a1); a2 = fmaf(acc, d2, a2);
      }
      part[wave * KMX + lane]       = a0;
      part[wave * KMX + lane + 64]  = a1;
      part[wave * KMX + lane + 128] = a2;
    }
    __syncthreads();                                   // (F)
    if (tid < KMX) {
      float gg = g_s[tid];
      #pragma unroll
      for (int w = 0; w < 16; ++w) gg -= part[w * KMX + tid];
      gg2 = gg;
    }
    if (wave < 3) {                                    // rho^2 = sum over 192 slots
      float r = gg2 * gg2;
      #pragma unroll
      for (int m = 1; m < 64; m <<= 1) r += __shfl_xor(r, m, 64);
      if (lane == 0) wsum_s[wave] = r;
    }
    __syncthreads();                                   // (G)
    const float rho = sqrtf(wsum_s[0] + wsum_s[1] + wsum_s[2]);
    if (tid < KMX) {
      float dj = gg2 / rho;
      g_s[tid] = dj;
      D[t * KMX + tid] = dj;                           // rows stay zero-padded (gg2=0 there)
    }
    if (tid == 0) item_sh = N;                         // reset for next iteration
    __syncthreads();                                   // (H)

    // ---- p_i -= (Gh_i . delta)^2 (fp16 loads, f32 accumulate), clamp >= 0 ----
    {
      float s0a = 0.f, s0b = 0.f, s1a = 0.f, s1b = 0.f;
      const __half* base2 = Gh + 2 * tid;
      for (int j = 0; j < kkr; j += 4) {
        float d0 = g_s[j], d1 = g_s[j + 1], d2 = g_s[j + 2], d3 = g_s[j + 3];
        float2 f0 = __half22float2(*(const __half2*)(base2 + (j + 0) * N));
        float2 f1 = __half22float2(*(const __half2*)(base2 + (j + 1) * N));
        float2 f2 = __half22float2(*(const __half2*)(base2 + (j + 2) * N));
        float2 f3 = __half22float2(*(const __half2*)(base2 + (j + 3) * N));
        s0a = fmaf(f0.x, d0, s0a); s1a = fmaf(f0.y, d0, s1a);
        s0b = fmaf(f1.x, d1, s0b); s1b = fmaf(f1.y, d1, s1b);
        s0a = fmaf(f2.x, d2, s0a); s1a = fmaf(f2.y, d2, s1a);
        s0b = fmaf(f3.x, d3, s0b); s1b = fmaf(f3.y, d3, s1b);
      }
      float s0 = s0a + s0b, s1 = s1a + s1b;
      p_s[2 * tid]     = fmaxf(p_s[2 * tid]     - s0 * s0, 0.f);
      p_s[2 * tid + 1] = fmaxf(p_s[2 * tid + 1] - s1 * s1, 0.f);
    }
    // p_s rows are thread-private; wsum_s/item_sh next writes are separated by barriers A/B.
  }
}

extern "C" void kernel_launch(void* const* d_in, const int* in_sizes, int n_in,
                              void* d_out, int out_size, void* d_ws, size_t ws_size,
                              hipStream_t stream) {
  (void)in_sizes; (void)n_in; (void)out_size; (void)ws_size;
  const float* e    = (const float*)d_in[0];
  const float* v    = (const float*)d_in[1];
  const int*   seed = (const int*)d_in[2];
  float* out = (float*)d_out;

  // ws layout: [0..32) hdr (kk, k, kloop0, kloop1); [32..800) sel[192];
  // [1KiB..145KiB) D (192x192 f32); [256KiB..1.75MiB) G (192x2048 f32, col-major);
  // [2MiB..2.75MiB) Gh (192x2048 fp16, col-major)
  int* hdr = (int*)d_ws;
  int* sel = hdr + 8;
  float*  D  = (float*)((char*)d_ws + 1024);
  float*  G  = (float*)((char*)d_ws + (size_t)256 * 1024);
  __half* Gh = (__half*)((char*)d_ws + (size_t)2048 * 1024);

  k_select<<<1, 256, 0, stream>>>(e, seed, hdr, sel);
  k_gather<<<dim3(8, KMX), 256, 0, stream>>>(v, hdr, sel, G, Gh);
  k_dpp_main<<<1, NTH, 0, stream>>>(hdr, G, Gh, D, out);
}

// Round 8
// 72.204 us; speedup vs baseline: 2.5159x; 1.5123x over previous
//
#include <hip/hip_runtime.h>
#include <hip/hip_fp16.h>
#include <stdint.h>
#include <stddef.h>

#define N 2048
#define KMX 192
#define NTH 1024

typedef _Float16 f16x2 __attribute__((ext_vector_type(2)));
typedef _Float16 f16x4 __attribute__((ext_vector_type(4)));

#if defined(__has_builtin)
#if __has_builtin(__builtin_amdgcn_fdot2)
#define HAS_FDOT2 1
#endif
#endif

__device__ __forceinline__ f16x2 bch2(unsigned u) { return __builtin_bit_cast(f16x2, u); }
__device__ __forceinline__ unsigned packh2(float a, float b) {
  unsigned ua = (unsigned)__half_as_ushort(__float2half(a));
  unsigned ub = (unsigned)__half_as_ushort(__float2half(b));
  return ua | (ub << 16);
}
__device__ __forceinline__ float dot2acc(unsigned c, unsigned y, float acc) {
#ifdef HAS_FDOT2
  return __builtin_amdgcn_fdot2(bch2(c), bch2(y), acc, false);
#else
  f16x2 cv = bch2(c), yv = bch2(y);
  acc = fmaf((float)cv[0], (float)yv[0], acc);
  acc = fmaf((float)cv[1], (float)yv[1], acc);
  return acc;
#endif
}

// ---------------- Threefry-2x32, JAX-compatible (20 rounds) ----------------
__device__ __forceinline__ void tfround(unsigned &x0, unsigned &x1, const int d) {
  x0 += x1;
  x1 = (x1 << d) | (x1 >> (32 - d));
  x1 ^= x0;
}

__device__ __forceinline__ uint2 tf2x32(unsigned k0, unsigned k1, unsigned c0, unsigned c1) {
  unsigned ks2 = k0 ^ k1 ^ 0x1BD11BDAu;
  unsigned x0 = c0 + k0, x1 = c1 + k1;
  tfround(x0,x1,13); tfround(x0,x1,15); tfround(x0,x1,26); tfround(x0,x1,6);
  x0 += k1;  x1 += ks2 + 1u;
  tfround(x0,x1,17); tfround(x0,x1,29); tfround(x0,x1,16); tfround(x0,x1,24);
  x0 += ks2; x1 += k0 + 2u;
  tfround(x0,x1,13); tfround(x0,x1,15); tfround(x0,x1,26); tfround(x0,x1,6);
  x0 += k0;  x1 += k1 + 3u;
  tfround(x0,x1,17); tfround(x0,x1,29); tfround(x0,x1,16); tfround(x0,x1,24);
  x0 += k1;  x1 += ks2 + 4u;
  tfround(x0,x1,13); tfround(x0,x1,15); tfround(x0,x1,26); tfround(x0,x1,6);
  x0 += ks2; x1 += k0 + 5u;
  uint2 r; r.x = x0; r.y = x1;
  return r;
}

// JAX uniform [0,1): (bits>>9 | 0x3f800000) bitcast - 1.0f  (exact)
__device__ __forceinline__ float u01(unsigned bits) {
  return __uint_as_float((bits >> 9) | 0x3f800000u) - 1.0f;
}

// ---------------- Kernel 1: Bernoulli selection + key derivation ----------------
__global__ void k_select(const float* __restrict__ e, const int* __restrict__ seedp,
                         int* __restrict__ hdr, int* __restrict__ sel) {
  __shared__ unsigned kx0, kx1;
  __shared__ int cnt_s[256];
  __shared__ int pre_s[256];
  const int tid = threadIdx.x;
  if (tid == 0) {
    unsigned seed = (unsigned)seedp[0];
    uint2 kidx  = tf2x32(0u, seed, 0u, 0u);
    uint2 kloop = tf2x32(0u, seed, 0u, 1u);
    kx0 = kidx.x; kx1 = kidx.y;
    hdr[2] = (int)kloop.x;
    hdr[3] = (int)kloop.y;
  }
  __syncthreads();
  const unsigned a0 = kx0, a1 = kx1;
  int flags = 0;
  #pragma unroll
  for (int r = 0; r < 8; ++r) {
    const int i = tid * 8 + r;
    uint2 o = tf2x32(a0, a1, 0u, (unsigned)i);
    float u = u01(o.x ^ o.y);
    float ev = e[i];
    float thr = ev / (ev + 1.0f);   // IEEE f32 div, matches XLA bit-exactly
    if (u < thr) flags |= (1 << r);
  }
  cnt_s[tid] = __popc(flags);
  __syncthreads();
  if (tid == 0) {
    int acc = 0;
    for (int t2 = 0; t2 < 256; ++t2) { pre_s[t2] = acc; acc += cnt_s[t2]; }
    hdr[1] = acc;
    hdr[0] = acc < KMX ? acc : KMX;
  }
  __syncthreads();
  int off = pre_s[tid];
  #pragma unroll
  for (int r = 0; r < 8; ++r) {
    if (flags & (1 << r)) {
      if (off < KMX) sel[off] = tid * 8 + r;
      ++off;
    }
  }
}

// ---------------- Kernel 2: gather G f32 + Gh fp16 mirror (col-major, zero-pad j>=kk) ----
__global__ void k_gather(const float* __restrict__ v, const int* __restrict__ hdr,
                         const int* __restrict__ sel, float* __restrict__ G,
                         __half* __restrict__ Gh) {
  const int j = blockIdx.y;
  const int i = blockIdx.x * 256 + threadIdx.x;
  float val = 0.f;
  if (j < hdr[0]) val = v[(size_t)i * N + sel[j]];
  G[j * N + i] = val;
  Gh[j * N + i] = __float2half(val);
}

// ---------------- Kernel 2b: Gram K = G^T G (fp16 out, f32 accum), 64x64 tiles ----------
__global__ void __launch_bounds__(256)
k_gram(const __half* __restrict__ Gh, const int* __restrict__ hdr,
       __half* __restrict__ Kh) {
  __shared__ __align__(16) __half As[32][64];
  __shared__ __align__(16) __half Bs[32][64];
  const int tid = threadIdx.x;
  const int i0 = blockIdx.y * 64;   // C rows
  const int i1 = blockIdx.x * 64;   // C cols
  const int tr = tid & 15, tc = tid >> 4;
  const int kk = hdr[0];
  int kc = (kk + 31) & ~31;
  if (kc > KMX) kc = KMX;

  float acc[4][4];
  #pragma unroll
  for (int r = 0; r < 4; ++r)
    #pragma unroll
    for (int c = 0; c < 4; ++c) acc[r][c] = 0.f;

  const int jr = tid >> 3, c8 = (tid & 7) * 8;
  for (int j0 = 0; j0 < kc; j0 += 32) {
    *(uint4*)&As[jr][c8] = *(const uint4*)(Gh + (size_t)(j0 + jr) * N + i0 + c8);
    *(uint4*)&Bs[jr][c8] = *(const uint4*)(Gh + (size_t)(j0 + jr) * N + i1 + c8);
    __syncthreads();
    #pragma unroll 8
    for (int k = 0; k < 32; ++k) {
      f16x4 a4 = *(const f16x4*)&As[k][tr * 4];
      f16x4 b4 = *(const f16x4*)&Bs[k][tc * 4];
      #pragma unroll
      for (int r = 0; r < 4; ++r)
        #pragma unroll
        for (int c = 0; c < 4; ++c)
          acc[r][c] = fmaf((float)a4[r], (float)b4[c], acc[r][c]);
    }
    __syncthreads();
  }
  #pragma unroll
  for (int r = 0; r < 4; ++r) {
    const int row = i0 + tr * 4 + r;
    uint2 w;
    w.x = packh2(acc[r][0], acc[r][1]);
    w.y = packh2(acc[r][2], acc[r][3]);
    *(uint2*)(Kh + (size_t)row * N + i1 + tc * 4) = w;
  }
}

// ---------------- Kernel 3 (new): Cholesky-style sequential DPP loop ----------------
// y^{(t)}_i = (K[r][i] - sum_{s<t} Y[s][r] Y[s][i]) / sqrt(p_r);  p_i -= y_i^2.
// Y stored fp16, pair-interleaved: YP[sp * N + i] = (half)(Y[2sp][i], Y[2sp+1][i]).
__global__ void __launch_bounds__(NTH)
k_dpp_chol(const int* __restrict__ hdr, const __half* __restrict__ Kh,
           unsigned* __restrict__ YP, float* __restrict__ out) {
  __shared__ float p_s[N];
  __shared__ unsigned cpack_s[KMX / 2];   // negated fp16 coefficient pairs
  __shared__ float u_s[KMX];
  __shared__ float wsum_s[16];
  __shared__ float rinv_sh;
  __shared__ int item_sh;

  const int tid  = threadIdx.x;
  const int lane = tid & 63;
  const int wave = tid >> 6;
  const int kk    = hdr[0];
  const int kfull = hdr[1];
  const unsigned kl0 = (unsigned)hdr[2];
  const unsigned kl1 = (unsigned)hdr[3];

  const float fill = (kfull == N) ? 1.0f : 0.0f;   // reference: k==n -> all ones
  out[tid] = fill;
  out[tid + NTH] = fill;
  if (kfull == N || kk == 0) return;

  // ---- init: p from K diagonal; precompute all u_t; reset item ----
  {
    const int i0 = 2 * tid;
    p_s[i0]     = (float)Kh[(size_t)i0 * N + i0];
    p_s[i0 + 1] = (float)Kh[(size_t)(i0 + 1) * N + i0 + 1];
    if (tid < KMX) {
      uint2 fk = tf2x32(kl0, kl1, 0u, (unsigned)tid);
      uint2 ob = tf2x32(fk.x, fk.y, 0u, 0u);
      u_s[tid] = u01(ob.x ^ ob.y);
    }
    if (tid == 0) item_sh = N;
  }
  __syncthreads();

  for (int t = 0; t < kk; ++t) {
    // ---- selection: first i with u < cumsum(p)_i / S ----
    float a  = p_s[2 * tid];
    float b  = p_s[2 * tid + 1];
    float ts = a + b;
    float ws = ts;
    #pragma unroll
    for (int d = 1; d < 64; d <<= 1) {
      float o = __shfl_up(ws, d, 64);
      if (lane >= d) ws += o;
    }
    if (lane == 63) wsum_s[wave] = ws;
    __syncthreads();                                   // (A)
    float S = 0.f, base_wave = 0.f;
    #pragma unroll
    for (int w = 0; w < 16; ++w) {
      float wv = wsum_s[w];
      if (w < wave) base_wave += wv;
      S += wv;
    }
    const float u = u_s[t];
    float excl = __shfl_up(ws, 1, 64);
    if (lane == 0) excl = 0.f;
    const float base = base_wave + excl;
    const float c0 = (base + a) / S;
    const float c1 = (base + ts) / S;
    const bool m0 = (u < c0);
    const bool m1 = (u < c1);
    unsigned long long bal = __ballot(m0 || m1);
    if (bal) {
      int first = (int)__builtin_ctzll(bal);
      if (lane == first) atomicMin(&item_sh, m0 ? 2 * tid : 2 * tid + 1);
    }
    __syncthreads();                                   // (B)
    int item = item_sh;
    if (item >= N) item = 0;                           // argmax(all False) == 0
    if (tid == 0) out[item] = 1.0f;
    if (t == kk - 1) break;                            // reference: m==1 -> no update

    // ---- coefficients c_s = -Y[s][item] (fp16 pairs, negated); rho; reset item ----
    if (tid < KMX / 2) {
      unsigned cu = 0;
      if (2 * tid < t) cu = YP[(size_t)tid * N + item] ^ 0x80008000u;
      cpack_s[tid] = cu;
    }
    if (tid == 0) {
      rinv_sh = 1.0f / sqrtf(fmaxf(p_s[item], 1e-30f));
      item_sh = N;
    }
    __syncthreads();                                   // (C)

    // ---- y = (K_row - Y^T c) * rinv; p -= y^2; append Y row t ----
    {
      const float rinv = rinv_sh;
      const int npair = (t + 1) >> 1;
      unsigned kp = *(const unsigned*)(Kh + (size_t)item * N + 2 * tid);
      f16x2 kv = bch2(kp);
      float acc0 = (float)kv[0], acc1 = (float)kv[1];
      for (int sp = 0; sp < npair; ++sp) {
        unsigned cs = cpack_s[sp];
        uint2 yv = *(const uint2*)(YP + (size_t)sp * N + 2 * tid);
        acc0 = dot2acc(cs, yv.x, acc0);
        acc1 = dot2acc(cs, yv.y, acc1);
      }
      float y0 = acc0 * rinv, y1 = acc1 * rinv;
      p_s[2 * tid]     = fmaxf(p_s[2 * tid]     - y0 * y0, 0.f);
      p_s[2 * tid + 1] = fmaxf(p_s[2 * tid + 1] - y1 * y1, 0.f);
      const int spt = t >> 1;
      if ((t & 1) == 0) {
        uint2 w;
        w.x = packh2(y0, 0.f);
        w.y = packh2(y1, 0.f);
        *(uint2*)(YP + (size_t)spt * N + 2 * tid) = w;
      } else {
        unsigned short* Ys = (unsigned short*)YP;
        Ys[((size_t)spt * N + 2 * tid) * 2 + 1]     = __half_as_ushort(__float2half(y0));
        Ys[((size_t)spt * N + 2 * tid + 1) * 2 + 1] = __half_as_ushort(__float2half(y1));
      }
    }
    // p_s rows thread-private; cpack/item/wsum next writes are behind barriers A/B/C.
  }
}

// ================= Fallback path (R7, proven): CGS2 projector tracking =================
__global__ void __launch_bounds__(NTH)
k_dpp_main(const int* __restrict__ hdr, const float* __restrict__ G,
           const __half* __restrict__ Gh, float* __restrict__ D,
           float* __restrict__ out) {
  __shared__ float p_s[N];
  __shared__ float g_s[KMX];
  __shared__ float part[16 * KMX];
  __shared__ float u_s[KMX];
  __shared__ float wsum_s[16];
  __shared__ int item_sh;

  const int tid  = threadIdx.x;
  const int lane = tid & 63;
  const int wave = tid >> 6;
  const int kk    = hdr[0];
  const int kfull = hdr[1];
  const unsigned kl0 = (unsigned)hdr[2];
  const unsigned kl1 = (unsigned)hdr[3];

  const float fill = (kfull == N) ? 1.0f : 0.0f;
  out[tid] = fill;
  out[tid + NTH] = fill;
  if (kfull == N || kk == 0) return;

  const int kkr = (kk + 15) & ~15;

  {
    float s0a = 0.f, s0b = 0.f, s1a = 0.f, s1b = 0.f;
    const __half* base = Gh + 2 * tid;
    for (int j = 0; j < kkr; j += 4) {
      float2 f0 = __half22float2(*(const __half2*)(base + (j + 0) * N));
      float2 f1 = __half22float2(*(const __half2*)(base + (j + 1) * N));
      float2 f2 = __half22float2(*(const __half2*)(base + (j + 2) * N));
      float2 f3 = __half22float2(*(const __half2*)(base + (j + 3) * N));
      s0a = fmaf(f0.x, f0.x, s0a); s1a = fmaf(f0.y, f0.y, s1a);
      s0b = fmaf(f1.x, f1.x, s0b); s1b = fmaf(f1.y, f1.y, s1b);
      s0a = fmaf(f2.x, f2.x, s0a); s1a = fmaf(f2.y, f2.y, s1a);
      s0b = fmaf(f3.x, f3.x, s0b); s1b = fmaf(f3.y, f3.y, s1b);
    }
    p_s[2 * tid]     = s0a + s0b;
    p_s[2 * tid + 1] = s1a + s1b;
    if (tid < KMX) {
      uint2 fk = tf2x32(kl0, kl1, 0u, (unsigned)tid);
      uint2 ob = tf2x32(fk.x, fk.y, 0u, 0u);
      u_s[tid] = u01(ob.x ^ ob.y);
    }
    if (tid == 0) item_sh = N;
  }
  __syncthreads();

  for (int t = 0; t < kk; ++t) {
    float a  = p_s[2 * tid];
    float b  = p_s[2 * tid + 1];
    float ts = a + b;
    float ws = ts;
    #pragma unroll
    for (int d = 1; d < 64; d <<= 1) {
      float o = __shfl_up(ws, d, 64);
      if (lane >= d) ws += o;
    }
    if (lane == 63) wsum_s[wave] = ws;
    __syncthreads();
    float S = 0.f, base_wave = 0.f;
    #pragma unroll
    for (int w = 0; w < 16; ++w) {
      float wv = wsum_s[w];
      if (w < wave) base_wave += wv;
      S += wv;
    }
    const float u = u_s[t];
    float excl = __shfl_up(ws, 1, 64);
    if (lane == 0) excl = 0.f;
    const float base = base_wave + excl;
    const float c0 = (base + a) / S;
    const float c1 = (base + ts) / S;
    const bool m0 = (u < c0);
    const bool m1 = (u < c1);
    unsigned long long bal = __ballot(m0 || m1);
    if (bal) {
      int first = (int)__builtin_ctzll(bal);
      if (lane == first) atomicMin(&item_sh, m0 ? 2 * tid : 2 * tid + 1);
    }
    __syncthreads();
    int item = item_sh;
    if (item >= N) item = 0;
    if (tid == 0) out[item] = 1.0f;
    if (t == kk - 1) break;

    if (tid < KMX) g_s[tid] = G[tid * N + item];
    __syncthreads();

    {
      float g0 = g_s[lane], g1 = g_s[lane + 64], g2 = g_s[lane + 128];
      float a0 = 0.f, a1 = 0.f, a2 = 0.f;
      for (int s = wave; s < t; s += 16) {
        const float* Dr = D + s * KMX;
        float d0 = Dr[lane], d1 = Dr[lane + 64], d2 = Dr[lane + 128];
        float acc = fmaf(d0, g0, fmaf(d1, g1, d2 * g2));
        #pragma unroll
        for (int m = 1; m < 64; m <<= 1) acc += __shfl_xor(acc, m, 64);
        a0 = fmaf(acc, d0, a0); a1 = fmaf(acc, d1, a1); a2 = fmaf(acc, d2, a2);
      }
      part[wave * KMX + lane]       = a0;
      part[wave * KMX + lane + 64]  = a1;
      part[wave * KMX + lane + 128] = a2;
    }
    __syncthreads();
    if (tid < KMX) {
      float gg = g_s[tid];
      #pragma unroll
      for (int w = 0; w < 16; ++w) gg -= part[w * KMX + tid];
      g_s[tid] = gg;
    }
    __syncthreads();

    float gg2 = 0.f;
    {
      float g0 = g_s[lane], g1 = g_s[lane + 64], g2 = g_s[lane + 128];
      float a0 = 0.f, a1 = 0.f, a2 = 0.f;
      for (int s = wave; s < t; s += 16) {
        const float* Dr = D + s * KMX;
        float d0 = Dr[lane], d1 = Dr[lane + 64], d2 = Dr[lane + 128];
        float acc = fmaf(d0, g0, fmaf(d1, g1, d2 * g2));
        #pragma unroll
        for (int m = 1; m < 64; m <<= 1) acc += __shfl_xor(acc, m, 64);
        a0 = fmaf(acc, d0, a0); a1 = fmaf(acc, d1, a1); a2 = fmaf(acc, d2, a2);
      }
      part[wave * KMX + lane]       = a0;
      part[wave * KMX + lane + 64]  = a1;
      part[wave * KMX + lane + 128] = a2;
    }
    __syncthreads();
    if (tid < KMX) {
      float gg = g_s[tid];
      #pragma unroll
      for (int w = 0; w < 16; ++w) gg -= part[w * KMX + tid];
      gg2 = gg;
    }
    if (wave < 3) {
      float r = gg2 * gg2;
      #pragma unroll
      for (int m = 1; m < 64; m <<= 1) r += __shfl_xor(r, m, 64);
      if (lane == 0) wsum_s[wave] = r;
    }
    __syncthreads();
    const float rho = sqrtf(wsum_s[0] + wsum_s[1] + wsum_s[2]);
    if (tid < KMX) {
      float dj = gg2 / rho;
      g_s[tid] = dj;
      D[t * KMX + tid] = dj;
    }
    if (tid == 0) item_sh = N;
    __syncthreads();

    {
      float s0a = 0.f, s0b = 0.f, s1a = 0.f, s1b = 0.f;
      const __half* base2 = Gh + 2 * tid;
      for (int j = 0; j < kkr; j += 4) {
        float d0 = g_s[j], d1 = g_s[j + 1], d2 = g_s[j + 2], d3 = g_s[j + 3];
        float2 f0 = __half22float2(*(const __half2*)(base2 + (j + 0) * N));
        float2 f1 = __half22float2(*(const __half2*)(base2 + (j + 1) * N));
        float2 f2 = __half22float2(*(const __half2*)(base2 + (j + 2) * N));
        float2 f3 = __half22float2(*(const __half2*)(base2 + (j + 3) * N));
        s0a = fmaf(f0.x, d0, s0a); s1a = fmaf(f0.y, d0, s1a);
        s0b = fmaf(f1.x, d1, s0b); s1b = fmaf(f1.y, d1, s1b);
        s0a = fmaf(f2.x, d2, s0a); s1a = fmaf(f2.y, d2, s1a);
        s0b = fmaf(f3.x, d3, s0b); s1b = fmaf(f3.y, d3, s1b);
      }
      float s0 = s0a + s0b, s1 = s1a + s1b;
      p_s[2 * tid]     = fmaxf(p_s[2 * tid]     - s0 * s0, 0.f);
      p_s[2 * tid + 1] = fmaxf(p_s[2 * tid + 1] - s1 * s1, 0.f);
    }
  }
}

extern "C" void kernel_launch(void* const* d_in, const int* in_sizes, int n_in,
                              void* d_out, int out_size, void* d_ws, size_t ws_size,
                              hipStream_t stream) {
  (void)in_sizes; (void)n_in; (void)out_size;
  const float* e    = (const float*)d_in[0];
  const float* v    = (const float*)d_in[1];
  const int*   seed = (const int*)d_in[2];
  float* out = (float*)d_out;

  int* hdr = (int*)d_ws;
  int* sel = hdr + 8;

  if (ws_size >= (size_t)12 * 1024 * 1024) {
    // New layout: Gh @4KB (768KB); G f32 @1MiB (1.5MB); YP @2.5MiB (768KB); Kh @4MiB (8MB)
    __half*   Gh = (__half*)((char*)d_ws + 4096);
    float*    G  = (float*)((char*)d_ws + (size_t)1024 * 1024);
    unsigned* YP = (unsigned*)((char*)d_ws + (size_t)2560 * 1024);
    __half*   Kh = (__half*)((char*)d_ws + (size_t)4096 * 1024);

    k_select<<<1, 256, 0, stream>>>(e, seed, hdr, sel);
    k_gather<<<dim3(8, KMX), 256, 0, stream>>>(v, hdr, sel, G, Gh);
    k_gram<<<dim3(32, 32), 256, 0, stream>>>(Gh, hdr, Kh);
    k_dpp_chol<<<1, NTH, 0, stream>>>(hdr, Kh, YP, out);
  } else {
    // Proven R7 layout: D @1KB; G f32 @256KB; Gh @2MiB
    float*  D  = (float*)((char*)d_ws + 1024);
    float*  G  = (float*)((char*)d_ws + (size_t)256 * 1024);
    __half* Gh = (__half*)((char*)d_ws + (size_t)2048 * 1024);

    k_select<<<1, 256, 0, stream>>>(e, seed, hdr, sel);
    k_gather<<<dim3(8, KMX), 256, 0, stream>>>(v, hdr, sel, G, Gh);
    k_dpp_main<<<1, NTH, 0, stream>>>(hdr, G, Gh, D, out);
  }
}

// Round 9
// 65.746 us; speedup vs baseline: 2.7630x; 1.0982x over previous
//
#include <hip/hip_runtime.h>
#include <hip/hip_fp16.h>
#include <stdint.h>
#include <stddef.h>

#define N 2048
#define KMX 192
#define NTH 1024

typedef _Float16 f16x2 __attribute__((ext_vector_type(2)));
typedef _Float16 f16x4 __attribute__((ext_vector_type(4)));

#if defined(__has_builtin)
#if __has_builtin(__builtin_amdgcn_fdot2)
#define HAS_FDOT2 1
#endif
#endif

__device__ __forceinline__ f16x2 bch2(unsigned u) { return __builtin_bit_cast(f16x2, u); }
__device__ __forceinline__ unsigned packh2(float a, float b) {
  unsigned ua = (unsigned)__half_as_ushort(__float2half(a));
  unsigned ub = (unsigned)__half_as_ushort(__float2half(b));
  return ua | (ub << 16);
}
__device__ __forceinline__ float dot2acc(unsigned c, unsigned y, float acc) {
#ifdef HAS_FDOT2
  return __builtin_amdgcn_fdot2(bch2(c), bch2(y), acc, false);
#else
  f16x2 cv = bch2(c), yv = bch2(y);
  acc = fmaf((float)cv[0], (float)yv[0], acc);
  acc = fmaf((float)cv[1], (float)yv[1], acc);
  return acc;
#endif
}

// ---------------- Threefry-2x32, JAX-compatible (20 rounds) ----------------
__device__ __forceinline__ void tfround(unsigned &x0, unsigned &x1, const int d) {
  x0 += x1;
  x1 = (x1 << d) | (x1 >> (32 - d));
  x1 ^= x0;
}

__device__ __forceinline__ uint2 tf2x32(unsigned k0, unsigned k1, unsigned c0, unsigned c1) {
  unsigned ks2 = k0 ^ k1 ^ 0x1BD11BDAu;
  unsigned x0 = c0 + k0, x1 = c1 + k1;
  tfround(x0,x1,13); tfround(x0,x1,15); tfround(x0,x1,26); tfround(x0,x1,6);
  x0 += k1;  x1 += ks2 + 1u;
  tfround(x0,x1,17); tfround(x0,x1,29); tfround(x0,x1,16); tfround(x0,x1,24);
  x0 += ks2; x1 += k0 + 2u;
  tfround(x0,x1,13); tfround(x0,x1,15); tfround(x0,x1,26); tfround(x0,x1,6);
  x0 += k0;  x1 += k1 + 3u;
  tfround(x0,x1,17); tfround(x0,x1,29); tfround(x0,x1,16); tfround(x0,x1,24);
  x0 += k1;  x1 += ks2 + 4u;
  tfround(x0,x1,13); tfround(x0,x1,15); tfround(x0,x1,26); tfround(x0,x1,6);
  x0 += ks2; x1 += k0 + 5u;
  uint2 r; r.x = x0; r.y = x1;
  return r;
}

// JAX uniform [0,1): (bits>>9 | 0x3f800000) bitcast - 1.0f  (exact)
__device__ __forceinline__ float u01(unsigned bits) {
  return __uint_as_float((bits >> 9) | 0x3f800000u) - 1.0f;
}

// ---------------- Kernel 1: Bernoulli selection + key derivation ----------------
__global__ void k_select(const float* __restrict__ e, const int* __restrict__ seedp,
                         int* __restrict__ hdr, int* __restrict__ sel) {
  __shared__ unsigned kx0, kx1;
  __shared__ int cnt_s[256];
  __shared__ int pre_s[256];
  const int tid = threadIdx.x;
  if (tid == 0) {
    unsigned seed = (unsigned)seedp[0];
    uint2 kidx  = tf2x32(0u, seed, 0u, 0u);
    uint2 kloop = tf2x32(0u, seed, 0u, 1u);
    kx0 = kidx.x; kx1 = kidx.y;
    hdr[2] = (int)kloop.x;
    hdr[3] = (int)kloop.y;
  }
  __syncthreads();
  const unsigned a0 = kx0, a1 = kx1;
  int flags = 0;
  #pragma unroll
  for (int r = 0; r < 8; ++r) {
    const int i = tid * 8 + r;
    uint2 o = tf2x32(a0, a1, 0u, (unsigned)i);
    float u = u01(o.x ^ o.y);
    float ev = e[i];
    float thr = ev / (ev + 1.0f);   // IEEE f32 div, matches XLA bit-exactly
    if (u < thr) flags |= (1 << r);
  }
  cnt_s[tid] = __popc(flags);
  __syncthreads();
  if (tid == 0) {
    int acc = 0;
    for (int t2 = 0; t2 < 256; ++t2) { pre_s[t2] = acc; acc += cnt_s[t2]; }
    hdr[1] = acc;
    hdr[0] = acc < KMX ? acc : KMX;
  }
  __syncthreads();
  int off = pre_s[tid];
  #pragma unroll
  for (int r = 0; r < 8; ++r) {
    if (flags & (1 << r)) {
      if (off < KMX) sel[off] = tid * 8 + r;
      ++off;
    }
  }
}

// ---------------- Kernel 2 (chol path): gather Gh fp16 only (col-major, zero-pad) ----
__global__ void k_gather_h(const float* __restrict__ v, const int* __restrict__ hdr,
                           const int* __restrict__ sel, __half* __restrict__ Gh) {
  const int j = blockIdx.y;
  const int i = blockIdx.x * 256 + threadIdx.x;
  float val = 0.f;
  if (j < hdr[0]) val = v[(size_t)i * N + sel[j]];
  Gh[j * N + i] = __float2half(val);
}

// ---------------- Kernel 2 (fallback path): gather G f32 + Gh fp16 mirror ----
__global__ void k_gather(const float* __restrict__ v, const int* __restrict__ hdr,
                         const int* __restrict__ sel, float* __restrict__ G,
                         __half* __restrict__ Gh) {
  const int j = blockIdx.y;
  const int i = blockIdx.x * 256 + threadIdx.x;
  float val = 0.f;
  if (j < hdr[0]) val = v[(size_t)i * N + sel[j]];
  G[j * N + i] = val;
  Gh[j * N + i] = __float2half(val);
}

// ---------------- Kernel 2b: Gram K = G^T G (fp16 out, f32 accum), 64x64 tiles ----------
__global__ void __launch_bounds__(256)
k_gram(const __half* __restrict__ Gh, const int* __restrict__ hdr,
       __half* __restrict__ Kh) {
  __shared__ __align__(16) __half As[32][64];
  __shared__ __align__(16) __half Bs[32][64];
  const int tid = threadIdx.x;
  const int i0 = blockIdx.y * 64;   // C rows
  const int i1 = blockIdx.x * 64;   // C cols
  const int tr = tid & 15, tc = tid >> 4;
  const int kk = hdr[0];
  int kc = (kk + 31) & ~31;
  if (kc > KMX) kc = KMX;

  float acc[4][4];
  #pragma unroll
  for (int r = 0; r < 4; ++r)
    #pragma unroll
    for (int c = 0; c < 4; ++c) acc[r][c] = 0.f;

  const int jr = tid >> 3, c8 = (tid & 7) * 8;
  for (int j0 = 0; j0 < kc; j0 += 32) {
    *(uint4*)&As[jr][c8] = *(const uint4*)(Gh + (size_t)(j0 + jr) * N + i0 + c8);
    *(uint4*)&Bs[jr][c8] = *(const uint4*)(Gh + (size_t)(j0 + jr) * N + i1 + c8);
    __syncthreads();
    #pragma unroll 8
    for (int k = 0; k < 32; ++k) {
      f16x4 a4 = *(const f16x4*)&As[k][tr * 4];
      f16x4 b4 = *(const f16x4*)&Bs[k][tc * 4];
      #pragma unroll
      for (int r = 0; r < 4; ++r)
        #pragma unroll
        for (int c = 0; c < 4; ++c)
          acc[r][c] = fmaf((float)a4[r], (float)b4[c], acc[r][c]);
    }
    __syncthreads();
  }
  #pragma unroll
  for (int r = 0; r < 4; ++r) {
    const int row = i0 + tr * 4 + r;
    uint2 w;
    w.x = packh2(acc[r][0], acc[r][1]);
    w.y = packh2(acc[r][2], acc[r][3]);
    *(uint2*)(Kh + (size_t)row * N + i1 + tc * 4) = w;
  }
}

// ---------------- Kernel 3: Cholesky-style sequential DPP loop (quad-packed Y) ------
// y^{(t)}_i = (K[r][i] - sum_{s<t} Y[s][r] Y[s][i]) / sqrt(p_r);  p_i -= y_i^2.
// YQ element (q, i) is a uint2 = 4 fp16 = Y[4q..4q+3][i]. Scan loads uint4 =
// 2 columns x 4 history (8 MACs / 16B / 4 fdot2). Stale tail slots are killed by
// masking the COEFFICIENT quad to zero, so reused workspace stays deterministic.
__global__ void __launch_bounds__(NTH)
k_dpp_chol(const int* __restrict__ hdr, const __half* __restrict__ Kh,
           uint2* __restrict__ YQ, float* __restrict__ out) {
  __shared__ float p_s[N];
  __shared__ uint2 cpack_s[KMX / 4];   // negated fp16 coefficient quads
  __shared__ float u_s[KMX];
  __shared__ float wsum_s[16];
  __shared__ float rinv_sh;
  __shared__ int item_sh;

  const int tid  = threadIdx.x;
  const int lane = tid & 63;
  const int wave = tid >> 6;
  const int kk    = hdr[0];
  const int kfull = hdr[1];
  const unsigned kl0 = (unsigned)hdr[2];
  const unsigned kl1 = (unsigned)hdr[3];

  const float fill = (kfull == N) ? 1.0f : 0.0f;   // reference: k==n -> all ones
  out[tid] = fill;
  out[tid + NTH] = fill;
  if (kfull == N || kk == 0) return;

  // ---- init: p from K diagonal; precompute all u_t; reset item ----
  {
    const int i0 = 2 * tid;
    p_s[i0]     = (float)Kh[(size_t)i0 * N + i0];
    p_s[i0 + 1] = (float)Kh[(size_t)(i0 + 1) * N + i0 + 1];
    if (tid < KMX) {
      uint2 fk = tf2x32(kl0, kl1, 0u, (unsigned)tid);
      uint2 ob = tf2x32(fk.x, fk.y, 0u, 0u);
      u_s[tid] = u01(ob.x ^ ob.y);
    }
    if (tid == 0) item_sh = N;
  }
  __syncthreads();

  for (int t = 0; t < kk; ++t) {
    // ---- selection: first i with u < cumsum(p)_i / S ----
    float a  = p_s[2 * tid];
    float b  = p_s[2 * tid + 1];
    float ts = a + b;
    float ws = ts;
    #pragma unroll
    for (int d = 1; d < 64; d <<= 1) {
      float o = __shfl_up(ws, d, 64);
      if (lane >= d) ws += o;
    }
    if (lane == 63) wsum_s[wave] = ws;
    __syncthreads();                                   // (A)
    float S = 0.f, base_wave = 0.f;
    #pragma unroll
    for (int w = 0; w < 16; ++w) {
      float wv = wsum_s[w];
      if (w < wave) base_wave += wv;
      S += wv;
    }
    const float Sinv = 1.0f / S;
    const float u = u_s[t];
    float excl = __shfl_up(ws, 1, 64);
    if (lane == 0) excl = 0.f;
    const float base = base_wave + excl;
    const float c0 = (base + a) * Sinv;
    const float c1 = (base + ts) * Sinv;
    const bool m0 = (u < c0);
    const bool m1 = (u < c1);
    unsigned long long bal = __ballot(m0 || m1);
    if (bal) {
      int first = (int)__builtin_ctzll(bal);
      if (lane == first) atomicMin(&item_sh, m0 ? 2 * tid : 2 * tid + 1);
    }
    __syncthreads();                                   // (B)
    int item = item_sh;
    if (item >= N) item = 0;                           // argmax(all False) == 0
    if (tid == 0) out[item] = 1.0f;
    if (t == kk - 1) break;                            // reference: m==1 -> no update

    // ---- coefficient quads c_q = -Y[4q..4q+3][item], tail-masked; rho; reset item ----
    if (tid * 4 < t) {
      uint2 cu = YQ[(size_t)tid * N + item];
      cu.x ^= 0x80008000u;
      cu.y ^= 0x80008000u;
      const int rem = t - 4 * tid;                     // valid slots in this quad (>=1)
      if (rem < 4) {
        if (rem == 1)      { cu.x &= 0x0000FFFFu; cu.y = 0u; }
        else if (rem == 2) { cu.y = 0u; }
        else               { cu.y &= 0x0000FFFFu; }    // rem == 3
      }
      cpack_s[tid] = cu;
    }
    if (tid == 0) {
      rinv_sh = 1.0f / sqrtf(fmaxf(p_s[item], 1e-30f));
      item_sh = N;
    }
    __syncthreads();                                   // (C)

    // ---- y = (K_row - Y^T c) * rinv; p -= y^2; append Y slot t ----
    {
      const float rinv = rinv_sh;
      const int nq = (t + 3) >> 2;
      unsigned kp = *(const unsigned*)(Kh + (size_t)item * N + 2 * tid);
      f16x2 kv = bch2(kp);
      float acc0 = (float)kv[0], acc1 = (float)kv[1];
      const uint2* Yp = YQ + 2 * tid;
      #pragma unroll 2
      for (int q = 0; q < nq; ++q) {
        uint2 cs = cpack_s[q];
        uint4 yv = *(const uint4*)(Yp + (size_t)q * N);  // cols 2tid,2tid+1 x 4 hist
        acc0 = dot2acc(cs.x, yv.x, acc0);
        acc0 = dot2acc(cs.y, yv.y, acc0);
        acc1 = dot2acc(cs.x, yv.z, acc1);
        acc1 = dot2acc(cs.y, yv.w, acc1);
      }
      float y0 = acc0 * rinv, y1 = acc1 * rinv;
      p_s[2 * tid]     = fmaxf(p_s[2 * tid]     - y0 * y0, 0.f);
      p_s[2 * tid + 1] = fmaxf(p_s[2 * tid + 1] - y1 * y1, 0.f);
      unsigned short* Ys = (unsigned short*)YQ;
      const size_t eb = ((size_t)(t >> 2) * N + 2 * tid) * 4;  // ushort index of elem
      Ys[eb + (t & 3)]     = __half_as_ushort(__float2half(y0));
      Ys[eb + 4 + (t & 3)] = __half_as_ushort(__float2half(y1));
    }
    // p_s rows thread-private; cpack/item/wsum next writes are behind barriers A/B/C.
  }
}

// ================= Fallback path (R7, proven): CGS2 projector tracking =================
__global__ void __launch_bounds__(NTH)
k_dpp_main(const int* __restrict__ hdr, const float* __restrict__ G,
           const __half* __restrict__ Gh, float* __restrict__ D,
           float* __restrict__ out) {
  __shared__ float p_s[N];
  __shared__ float g_s[KMX];
  __shared__ float part[16 * KMX];
  __shared__ float u_s[KMX];
  __shared__ float wsum_s[16];
  __shared__ int item_sh;

  const int tid  = threadIdx.x;
  const int lane = tid & 63;
  const int wave = tid >> 6;
  const int kk    = hdr[0];
  const int kfull = hdr[1];
  const unsigned kl0 = (unsigned)hdr[2];
  const unsigned kl1 = (unsigned)hdr[3];

  const float fill = (kfull == N) ? 1.0f : 0.0f;
  out[tid] = fill;
  out[tid + NTH] = fill;
  if (kfull == N || kk == 0) return;

  const int kkr = (kk + 15) & ~15;

  {
    float s0a = 0.f, s0b = 0.f, s1a = 0.f, s1b = 0.f;
    const __half* base = Gh + 2 * tid;
    for (int j = 0; j < kkr; j += 4) {
      float2 f0 = __half22float2(*(const __half2*)(base + (j + 0) * N));
      float2 f1 = __half22float2(*(const __half2*)(base + (j + 1) * N));
      float2 f2 = __half22float2(*(const __half2*)(base + (j + 2) * N));
      float2 f3 = __half22float2(*(const __half2*)(base + (j + 3) * N));
      s0a = fmaf(f0.x, f0.x, s0a); s1a = fmaf(f0.y, f0.y, s1a);
      s0b = fmaf(f1.x, f1.x, s0b); s1b = fmaf(f1.y, f1.y, s1b);
      s0a = fmaf(f2.x, f2.x, s0a); s1a = fmaf(f2.y, f2.y, s1a);
      s0b = fmaf(f3.x, f3.x, s0b); s1b = fmaf(f3.y, f3.y, s1b);
    }
    p_s[2 * tid]     = s0a + s0b;
    p_s[2 * tid + 1] = s1a + s1b;
    if (tid < KMX) {
      uint2 fk = tf2x32(kl0, kl1, 0u, (unsigned)tid);
      uint2 ob = tf2x32(fk.x, fk.y, 0u, 0u);
      u_s[tid] = u01(ob.x ^ ob.y);
    }
    if (tid == 0) item_sh = N;
  }
  __syncthreads();

  for (int t = 0; t < kk; ++t) {
    float a  = p_s[2 * tid];
    float b  = p_s[2 * tid + 1];
    float ts = a + b;
    float ws = ts;
    #pragma unroll
    for (int d = 1; d < 64; d <<= 1) {
      float o = __shfl_up(ws, d, 64);
      if (lane >= d) ws += o;
    }
    if (lane == 63) wsum_s[wave] = ws;
    __syncthreads();
    float S = 0.f, base_wave = 0.f;
    #pragma unroll
    for (int w = 0; w < 16; ++w) {
      float wv = wsum_s[w];
      if (w < wave) base_wave += wv;
      S += wv;
    }
    const float u = u_s[t];
    float excl = __shfl_up(ws, 1, 64);
    if (lane == 0) excl = 0.f;
    const float base = base_wave + excl;
    const float c0 = (base + a) / S;
    const float c1 = (base + ts) / S;
    const bool m0 = (u < c0);
    const bool m1 = (u < c1);
    unsigned long long bal = __ballot(m0 || m1);
    if (bal) {
      int first = (int)__builtin_ctzll(bal);
      if (lane == first) atomicMin(&item_sh, m0 ? 2 * tid : 2 * tid + 1);
    }
    __syncthreads();
    int item = item_sh;
    if (item >= N) item = 0;
    if (tid == 0) out[item] = 1.0f;
    if (t == kk - 1) break;

    if (tid < KMX) g_s[tid] = G[tid * N + item];
    __syncthreads();

    {
      float g0 = g_s[lane], g1 = g_s[lane + 64], g2 = g_s[lane + 128];
      float a0 = 0.f, a1 = 0.f, a2 = 0.f;
      for (int s = wave; s < t; s += 16) {
        const float* Dr = D + s * KMX;
        float d0 = Dr[lane], d1 = Dr[lane + 64], d2 = Dr[lane + 128];
        float acc = fmaf(d0, g0, fmaf(d1, g1, d2 * g2));
        #pragma unroll
        for (int m = 1; m < 64; m <<= 1) acc += __shfl_xor(acc, m, 64);
        a0 = fmaf(acc, d0, a0); a1 = fmaf(acc, d1, a1); a2 = fmaf(acc, d2, a2);
      }
      part[wave * KMX + lane]       = a0;
      part[wave * KMX + lane + 64]  = a1;
      part[wave * KMX + lane + 128] = a2;
    }
    __syncthreads();
    if (tid < KMX) {
      float gg = g_s[tid];
      #pragma unroll
      for (int w = 0; w < 16; ++w) gg -= part[w * KMX + tid];
      g_s[tid] = gg;
    }
    __syncthreads();

    float gg2 = 0.f;
    {
      float g0 = g_s[lane], g1 = g_s[lane + 64], g2 = g_s[lane + 128];
      float a0 = 0.f, a1 = 0.f, a2 = 0.f;
      for (int s = wave; s < t; s += 16) {
        const float* Dr = D + s * KMX;
        float d0 = Dr[lane], d1 = Dr[lane + 64], d2 = Dr[lane + 128];
        float acc = fmaf(d0, g0, fmaf(d1, g1, d2 * g2));
        #pragma unroll
        for (int m = 1; m < 64; m <<= 1) acc += __shfl_xor(acc, m, 64);
        a0 = fmaf(acc, d0, a0); a1 = fmaf(acc, d1, a1); a2 = fmaf(acc, d2, a2);
      }
      part[wave * KMX + lane]       = a0;
      part[wave * KMX + lane + 64]  = a1;
      part[wave * KMX + lane + 128] = a2;
    }
    __syncthreads();
    if (tid < KMX) {
      float gg = g_s[tid];
      #pragma unroll
      for (int w = 0; w < 16; ++w) gg -= part[w * KMX + tid];
      gg2 = gg;
    }
    if (wave < 3) {
      float r = gg2 * gg2;
      #pragma unroll
      for (int m = 1; m < 64; m <<= 1) r += __shfl_xor(r, m, 64);
      if (lane == 0) wsum_s[wave] = r;
    }
    __syncthreads();
    const float rho = sqrtf(wsum_s[0] + wsum_s[1] + wsum_s[2]);
    if (tid < KMX) {
      float dj = gg2 / rho;
      g_s[tid] = dj;
      D[t * KMX + tid] = dj;
    }
    if (tid == 0) item_sh = N;
    __syncthreads();

    {
      float s0a = 0.f, s0b = 0.f, s1a = 0.f, s1b = 0.f;
      const __half* base2 = Gh + 2 * tid;
      for (int j = 0; j < kkr; j += 4) {
        float d0 = g_s[j], d1 = g_s[j + 1], d2 = g_s[j + 2], d3 = g_s[j + 3];
        float2 f0 = __half22float2(*(const __half2*)(base2 + (j + 0) * N));
        float2 f1 = __half22float2(*(const __half2*)(base2 + (j + 1) * N));
        float2 f2 = __half22float2(*(const __half2*)(base2 + (j + 2) * N));
        float2 f3 = __half22float2(*(const __half2*)(base2 + (j + 3) * N));
        s0a = fmaf(f0.x, d0, s0a); s1a = fmaf(f0.y, d0, s1a);
        s0b = fmaf(f1.x, d1, s0b); s1b = fmaf(f1.y, d1, s1b);
        s0a = fmaf(f2.x, d2, s0a); s1a = fmaf(f2.y, d2, s1a);
        s0b = fmaf(f3.x, d3, s0b); s1b = fmaf(f3.y, d3, s1b);
      }
      float s0 = s0a + s0b, s1 = s1a + s1b;
      p_s[2 * tid]     = fmaxf(p_s[2 * tid]     - s0 * s0, 0.f);
      p_s[2 * tid + 1] = fmaxf(p_s[2 * tid + 1] - s1 * s1, 0.f);
    }
  }
}

extern "C" void kernel_launch(void* const* d_in, const int* in_sizes, int n_in,
                              void* d_out, int out_size, void* d_ws, size_t ws_size,
                              hipStream_t stream) {
  (void)in_sizes; (void)n_in; (void)out_size;
  const float* e    = (const float*)d_in[0];
  const float* v    = (const float*)d_in[1];
  const int*   seed = (const int*)d_in[2];
  float* out = (float*)d_out;

  int* hdr = (int*)d_ws;
  int* sel = hdr + 8;

  if (ws_size >= (size_t)12 * 1024 * 1024) {
    // Layout: Gh @4KB (768KB); YQ @2.5MiB (768KB, quad-packed); Kh @4MiB (8MB)
    __half* Gh = (__half*)((char*)d_ws + 4096);
    uint2*  YQ = (uint2*)((char*)d_ws + (size_t)2560 * 1024);
    __half* Kh = (__half*)((char*)d_ws + (size_t)4096 * 1024);

    k_select<<<1, 256, 0, stream>>>(e, seed, hdr, sel);
    k_gather_h<<<dim3(8, KMX), 256, 0, stream>>>(v, hdr, sel, Gh);
    k_gram<<<dim3(32, 32), 256, 0, stream>>>(Gh, hdr, Kh);
    k_dpp_chol<<<1, NTH, 0, stream>>>(hdr, Kh, YQ, out);
  } else {
    // Proven R7 layout: D @1KB; G f32 @256KB; Gh @2MiB
    float*  D  = (float*)((char*)d_ws + 1024);
    float*  G  = (float*)((char*)d_ws + (size_t)256 * 1024);
    __half* Gh = (__half*)((char*)d_ws + (size_t)2048 * 1024);

    k_select<<<1, 256, 0, stream>>>(e, seed, hdr, sel);
    k_gather<<<dim3(8, KMX), 256, 0, stream>>>(v, hdr, sel, G, Gh);
    k_dpp_main<<<1, NTH, 0, stream>>>(hdr, G, Gh, D, out);
  }
}